// Round 5
// baseline (151618.677 us; speedup 1.0000x reference)
//
#include <hip/hip_runtime.h>
#include <stdint.h>

// LSTMEncoder: T=8192, IN_DIM=512, H=1024, 2 layers, fp32.
// Phases (all on `stream`, serialized by stream order):
//   1. nan_fill(h1), nan_fill(d_out)          -- sentinel init (system-scope stores)
//   2. gemm: xg = x @ W_ih_0 + b_0            -- [8192,512]@[512,4096]
//   3. scan layer 0 -> h1 (persistent dataflow, sentinel sync)
//   4. gemm: xg = h1 @ W_ih_1 + b_1           -- [8192,1024]@[1024,4096]
//   5. scan layer 1 -> d_out
// Workspace: xg (128 MB) + h1 (32 MB) = 160 MB.
//
// R5 change vs R4: scan poll traffic was the bottleneck (FETCH 1.5 GB/scan,
// 9.2 us/step). Now 128 blocks (not 256), 8 units/block, 2 units/wave;
// each lane polls ONLY its own 128-float h-slice (the poll IS the data
// load). Aggregate sweep traffic 4 MB -> 2 MB, pollers 1024 -> 512 waves.

#define TT    8192
#define INDIM 512
#define HH    1024
#define G4    4096   // 4*H
#define NBLK  128    // scan blocks
#define UPB   8      // units per block

#define SENT 0x7FC00000u  // NaN sentinel bit pattern

typedef float f32x4 __attribute__((ext_vector_type(4)));  // direct VGPR tuple for asm "v"

__device__ __forceinline__ float sigf(float x) { return 1.0f / (1.0f + __expf(-x)); }

// ---------------------------------------------------------------------------
// Sentinel init: fill region with NaN using system-scope stores.
// ---------------------------------------------------------------------------
__global__ void nan_fill_kernel(float* __restrict__ p, long n) {
  float sv = __uint_as_float(SENT);
  long i = (long)blockIdx.x * blockDim.x + threadIdx.x;
  long stride = (long)gridDim.x * blockDim.x;
  for (; i < n; i += stride) {
    __hip_atomic_store(p + i, sv, __ATOMIC_RELAXED, __HIP_MEMORY_SCOPE_SYSTEM);
  }
}

// ---------------------------------------------------------------------------
// fp32 GEMM with bias: C[M,N] = A[M,K] @ B[K,N] + bias[N]
// BM=BN=128, BK=16, 256 threads, 8x8 per thread. (unchanged from R4; passed)
// ---------------------------------------------------------------------------
__global__ __launch_bounds__(256, 2) void gemm_bias_f32(
    const float* __restrict__ A, const float* __restrict__ B,
    const float* __restrict__ bias, float* __restrict__ C,
    int M, int N, int K)
{
  constexpr int BM = 128, BN = 128, BK = 16, TM = 8, TN = 8;
  __shared__ float As[BK][BM];   // transposed A tile
  __shared__ float Bs[BK][BN];
  const int tid = threadIdx.x;
  const int bm = blockIdx.y * BM;
  const int bn = blockIdx.x * BN;
  const int tm = (tid >> 4) * TM;
  const int tn = (tid & 15) * TN;
  float acc[TM][TN] = {};
  for (int k0 = 0; k0 < K; k0 += BK) {
    #pragma unroll
    for (int i = 0; i < 2; ++i) {
      int idx = tid * 2 + i;
      int r = idx >> 2, c4 = idx & 3;
      float4 a = *(const float4*)(A + (size_t)(bm + r) * K + k0 + c4 * 4);
      As[c4 * 4 + 0][r] = a.x;
      As[c4 * 4 + 1][r] = a.y;
      As[c4 * 4 + 2][r] = a.z;
      As[c4 * 4 + 3][r] = a.w;
    }
    #pragma unroll
    for (int i = 0; i < 2; ++i) {
      int idx = tid * 2 + i;
      int r = idx >> 5, c4 = idx & 31;
      *(float4*)&Bs[r][c4 * 4] = *(const float4*)(B + (size_t)(k0 + r) * N + bn + c4 * 4);
    }
    __syncthreads();
    #pragma unroll
    for (int kk = 0; kk < BK; ++kk) {
      float ar[TM], br[TN];
      *(float4*)&ar[0] = *(const float4*)&As[kk][tm];
      *(float4*)&ar[4] = *(const float4*)&As[kk][tm + 4];
      *(float4*)&br[0] = *(const float4*)&Bs[kk][tn];
      *(float4*)&br[4] = *(const float4*)&Bs[kk][tn + 4];
      #pragma unroll
      for (int i = 0; i < TM; ++i)
        #pragma unroll
        for (int j = 0; j < TN; ++j)
          acc[i][j] = fmaf(ar[i], br[j], acc[i][j]);
    }
    __syncthreads();
  }
  #pragma unroll
  for (int i = 0; i < TM; ++i) {
    float* crow = C + (size_t)(bm + tm + i) * N + bn + tn;
    #pragma unroll
    for (int j = 0; j < TN; j += 4) {
      float4 v;
      v.x = acc[i][j + 0] + bias[bn + tn + j + 0];
      v.y = acc[i][j + 1] + bias[bn + tn + j + 1];
      v.z = acc[i][j + 2] + bias[bn + tn + j + 2];
      v.w = acc[i][j + 3] + bias[bn + tn + j + 3];
      *(float4*)(crow + j) = v;
    }
  }
}

// ---------------------------------------------------------------------------
// Persistent LSTM scan. 128 wgs x 256 threads = 512 waves; 8 units/block,
// 2 units/wave. Lane l: pair pr=l>>3 -> (gate=pr&3, unit-half ul=pr>>2);
// slice q=l&7 owns h[q*128 .. q*128+128). Each lane holds 128 W_hh weights
// in VGPRs. Poll = re-load own slice (sc0/sc1, L2-bypassing) until no NaN
// sentinel; the successful poll IS the data (no separate flag round-trip).
// Reduce: 3x shfl_xor over the 8 slice-lanes of a pair; gates broadcast
// within 32-lane unit-halves. No LDS, no __syncthreads.
// ---------------------------------------------------------------------------
__global__ __launch_bounds__(256, 1) void lstm_scan_kernel(
    const float* __restrict__ xg,    // [T][4096], bias already folded in
    const float* __restrict__ Whh,   // [H][4096]
    float* __restrict__ hout,        // [T][H], pre-filled with NaN sentinel
    int nsteps)
{
  const int tid = threadIdx.x;
  const int w = tid >> 6;           // wave in block
  const int l = tid & 63;
  const int pr = l >> 3;            // pair 0..7: (gate, unit-half)
  const int q  = l & 7;             // h-slice index 0..7
  const int gate = pr & 3;
  const int ul = pr >> 2;           // 0..1
  const int u = blockIdx.x * UPB + w * 2 + ul;   // hidden unit 0..1023
  const int col = gate * HH + u;                 // gate column in [0,4096)

  // Preload this lane's 128 weights: W_hh[q*128+j][col], j=0..127.
  float wr[128];
  #pragma unroll
  for (int j = 0; j < 128; ++j)
    wr[j] = Whh[(size_t)(q * 128 + j) * G4 + col];

  float c = 0.0f;
  float xgv = xg[col];              // prefetched xg for t=0
  uint32_t budget = (1u << 20);     // anti-hang safety valve

  for (int t = 0; t < nsteps; ++t) {
    float xg_cur = xgv;
    int tn = (t + 1 < nsteps) ? t + 1 : t;
    xgv = xg[(size_t)tn * G4 + col];   // prefetch next step's xg (cached ok)

    float red = 0.0f;
    if (t > 0) {
      const float* hs = hout + (size_t)(t - 1) * HH + q * 128;  // own slice
      f32x4 hv[32];
      int done = 0;
      do {
        asm volatile(
          "global_load_dwordx4 %0,  %16, off sc0 sc1\n\t"
          "global_load_dwordx4 %1,  %16, off offset:16 sc0 sc1\n\t"
          "global_load_dwordx4 %2,  %16, off offset:32 sc0 sc1\n\t"
          "global_load_dwordx4 %3,  %16, off offset:48 sc0 sc1\n\t"
          "global_load_dwordx4 %4,  %16, off offset:64 sc0 sc1\n\t"
          "global_load_dwordx4 %5,  %16, off offset:80 sc0 sc1\n\t"
          "global_load_dwordx4 %6,  %16, off offset:96 sc0 sc1\n\t"
          "global_load_dwordx4 %7,  %16, off offset:112 sc0 sc1\n\t"
          "global_load_dwordx4 %8,  %16, off offset:128 sc0 sc1\n\t"
          "global_load_dwordx4 %9,  %16, off offset:144 sc0 sc1\n\t"
          "global_load_dwordx4 %10, %16, off offset:160 sc0 sc1\n\t"
          "global_load_dwordx4 %11, %16, off offset:176 sc0 sc1\n\t"
          "global_load_dwordx4 %12, %16, off offset:192 sc0 sc1\n\t"
          "global_load_dwordx4 %13, %16, off offset:208 sc0 sc1\n\t"
          "global_load_dwordx4 %14, %16, off offset:224 sc0 sc1\n\t"
          "global_load_dwordx4 %15, %16, off offset:240 sc0 sc1"
          : "=v"(hv[0]), "=v"(hv[1]), "=v"(hv[2]), "=v"(hv[3]),
            "=v"(hv[4]), "=v"(hv[5]), "=v"(hv[6]), "=v"(hv[7]),
            "=v"(hv[8]), "=v"(hv[9]), "=v"(hv[10]), "=v"(hv[11]),
            "=v"(hv[12]), "=v"(hv[13]), "=v"(hv[14]), "=v"(hv[15])
          : "v"(hs));
        asm volatile(
          "global_load_dwordx4 %0,  %16, off offset:256 sc0 sc1\n\t"
          "global_load_dwordx4 %1,  %16, off offset:272 sc0 sc1\n\t"
          "global_load_dwordx4 %2,  %16, off offset:288 sc0 sc1\n\t"
          "global_load_dwordx4 %3,  %16, off offset:304 sc0 sc1\n\t"
          "global_load_dwordx4 %4,  %16, off offset:320 sc0 sc1\n\t"
          "global_load_dwordx4 %5,  %16, off offset:336 sc0 sc1\n\t"
          "global_load_dwordx4 %6,  %16, off offset:352 sc0 sc1\n\t"
          "global_load_dwordx4 %7,  %16, off offset:368 sc0 sc1\n\t"
          "global_load_dwordx4 %8,  %16, off offset:384 sc0 sc1\n\t"
          "global_load_dwordx4 %9,  %16, off offset:400 sc0 sc1\n\t"
          "global_load_dwordx4 %10, %16, off offset:416 sc0 sc1\n\t"
          "global_load_dwordx4 %11, %16, off offset:432 sc0 sc1\n\t"
          "global_load_dwordx4 %12, %16, off offset:448 sc0 sc1\n\t"
          "global_load_dwordx4 %13, %16, off offset:464 sc0 sc1\n\t"
          "global_load_dwordx4 %14, %16, off offset:480 sc0 sc1\n\t"
          "global_load_dwordx4 %15, %16, off offset:496 sc0 sc1"
          : "=v"(hv[16]), "=v"(hv[17]), "=v"(hv[18]), "=v"(hv[19]),
            "=v"(hv[20]), "=v"(hv[21]), "=v"(hv[22]), "=v"(hv[23]),
            "=v"(hv[24]), "=v"(hv[25]), "=v"(hv[26]), "=v"(hv[27]),
            "=v"(hv[28]), "=v"(hv[29]), "=v"(hv[30]), "=v"(hv[31])
          : "v"(hs));
        asm volatile("s_waitcnt vmcnt(0)" ::: "memory");
        __builtin_amdgcn_sched_barrier(0);  // rule #18: don't hoist uses past waitcnt
        int valid = 1;
        #pragma unroll
        for (int k = 0; k < 32; ++k) {
          valid &= (__float_as_uint(hv[k].x) != SENT);
          valid &= (__float_as_uint(hv[k].y) != SENT);
          valid &= (__float_as_uint(hv[k].z) != SENT);
          valid &= (__float_as_uint(hv[k].w) != SENT);
        }
        done = __all(valid);
        if (!done) --budget;
      } while (!done && budget);
      if (!done) {
        // Safety valve: sanitize so we terminate; validation fails loudly.
        #pragma unroll
        for (int k = 0; k < 32; ++k) {
          if (__float_as_uint(hv[k].x) == SENT) hv[k].x = 0.0f;
          if (__float_as_uint(hv[k].y) == SENT) hv[k].y = 0.0f;
          if (__float_as_uint(hv[k].z) == SENT) hv[k].z = 0.0f;
          if (__float_as_uint(hv[k].w) == SENT) hv[k].w = 0.0f;
        }
      }
      // 128 MACs, 4 independent chains
      float s0 = 0.f, s1 = 0.f, s2 = 0.f, s3 = 0.f;
      #pragma unroll
      for (int k = 0; k < 32; ++k) {
        s0 = fmaf(wr[4 * k + 0], hv[k].x, s0);
        s1 = fmaf(wr[4 * k + 1], hv[k].y, s1);
        s2 = fmaf(wr[4 * k + 2], hv[k].z, s2);
        s3 = fmaf(wr[4 * k + 3], hv[k].w, s3);
      }
      red = (s0 + s1) + (s2 + s3);
      // reduce across the 8 slice-lanes of this pair (xor masks 1,2,4)
      red += __shfl_xor(red, 1, 64);
      red += __shfl_xor(red, 2, 64);
      red += __shfl_xor(red, 4, 64);
    }

    float gp = red + xg_cur;       // pre-activation for (gate, unit) of this pair
    // gates of THIS lane's unit live at lanes (l&32)+{0,8,16,24}
    int base = l & 32;
    float gi_ = __shfl(gp, base + 0, 64);
    float gf_ = __shfl(gp, base + 8, 64);
    float gg_ = __shfl(gp, base + 16, 64);
    float go_ = __shfl(gp, base + 24, 64);
    float iv = sigf(gi_);
    float fv = sigf(gf_);
    float gv = tanhf(gg_);
    float ov = sigf(go_);
    c = fv * c + iv * gv;          // replicated across the unit's 32 lanes
    float h = ov * tanhf(c);
    if ((l & 31) == 0) {           // lanes 0 and 32: one store per unit
      __hip_atomic_store(hout + (size_t)t * HH + u, h,
                         __ATOMIC_RELAXED, __HIP_MEMORY_SCOPE_SYSTEM);
    }
  }
}

// ---------------------------------------------------------------------------
extern "C" void kernel_launch(void* const* d_in, const int* in_sizes, int n_in,
                              void* d_out, int out_size, void* d_ws, size_t ws_size,
                              hipStream_t stream)
{
  const float* x    = (const float*)d_in[0];
  const float* Wih0 = (const float*)d_in[1];
  const float* Whh0 = (const float*)d_in[2];
  const float* b0   = (const float*)d_in[3];
  const float* Wih1 = (const float*)d_in[4];
  const float* Whh1 = (const float*)d_in[5];
  const float* b1   = (const float*)d_in[6];
  float* out = (float*)d_out;

  float* ws    = (float*)d_ws;
  float* xgbuf = ws;                        // TT*G4 floats (128 MB), reused by both layers
  float* h1    = ws + (size_t)TT * G4;      // TT*HH floats (32 MB)

  // 1. sentinel init of both h histories
  nan_fill_kernel<<<2048, 256, 0, stream>>>(h1, (long)TT * HH);
  nan_fill_kernel<<<2048, 256, 0, stream>>>(out, (long)TT * HH);

  dim3 gblk(256);
  dim3 ggrid(G4 / 128, TT / 128);

  // 2. xg = x @ W_ih_0 + b_0
  gemm_bias_f32<<<ggrid, gblk, 0, stream>>>(x, Wih0, b0, xgbuf, TT, G4, INDIM);
  // 3. layer-0 scan -> h1
  lstm_scan_kernel<<<NBLK, 256, 0, stream>>>(xgbuf, Whh0, h1, TT);
  // 4. xg = h1 @ W_ih_1 + b_1
  gemm_bias_f32<<<ggrid, gblk, 0, stream>>>(h1, Wih1, b1, xgbuf, TT, G4, HH);
  // 5. layer-1 scan -> d_out (d_out IS the h2 history)
  lstm_scan_kernel<<<NBLK, 256, 0, stream>>>(xgbuf, Whh1, out, TT);
}

// Round 6
// 83483.063 us; speedup vs baseline: 1.8162x; 1.8162x over previous
//
#include <hip/hip_runtime.h>
#include <stdint.h>

// LSTMEncoder: T=8192, IN_DIM=512, H=1024, 2 layers, fp32.
//   1. nan_fill(h1), nan_fill(d_out), zero(flags)
//   2. gemm: xg = x @ W_ih_0 + b_0
//   3. scan layer 0 -> h1            (flag-gated dataflow)
//   4. zero(flags); gemm: xg = h1 @ W_ih_1 + b_1
//   5. scan layer 1 -> d_out
// Workspace: xg 128 MB + h1 32 MB + flags 8 MB = 168 MB.
//
// R6 vs R4/R5: R5 regressed (fatter lanes, same aggregate poll traffic).
// Root cause model: repeated 4KB-per-wave data polling congests the fabric
// and quantizes the wait (vmcnt(0) sweeps). Now: producers set a per-block
// flag AFTER h stores drain (__syncthreads implies vmcnt(0)); consumers
// poll 256 flag dwords (one dwordx4 per lane) with s_sleep backoff, then
// read the h row ONCE. NaN-sentinel check on data retained as a backstop,
// so correctness semantics are identical to R4 (verified passing).

#define TT    8192
#define INDIM 512
#define HH    1024
#define G4    4096   // 4*H
#define NBLK  256    // scan blocks (= flag row width)

#define SENT 0x7FC00000u  // NaN sentinel bit pattern

typedef float    f32x4 __attribute__((ext_vector_type(4)));
typedef uint32_t u32x4 __attribute__((ext_vector_type(4)));

__device__ __forceinline__ float sigf(float x) { return 1.0f / (1.0f + __expf(-x)); }

// ---------------------------------------------------------------------------
// Sentinel init: fill region with NaN using system-scope stores.
// ---------------------------------------------------------------------------
__global__ void nan_fill_kernel(float* __restrict__ p, long n) {
  float sv = __uint_as_float(SENT);
  long i = (long)blockIdx.x * blockDim.x + threadIdx.x;
  long stride = (long)gridDim.x * blockDim.x;
  for (; i < n; i += stride) {
    __hip_atomic_store(p + i, sv, __ATOMIC_RELAXED, __HIP_MEMORY_SCOPE_SYSTEM);
  }
}

// ---------------------------------------------------------------------------
// Zero init for the flag array (system-scope so pollers never see stale 1s).
// ---------------------------------------------------------------------------
__global__ void zero_fill_kernel(uint32_t* __restrict__ p, long n) {
  long i = (long)blockIdx.x * blockDim.x + threadIdx.x;
  long stride = (long)gridDim.x * blockDim.x;
  for (; i < n; i += stride) {
    __hip_atomic_store(p + i, 0u, __ATOMIC_RELAXED, __HIP_MEMORY_SCOPE_SYSTEM);
  }
}

// ---------------------------------------------------------------------------
// fp32 GEMM with bias: C[M,N] = A[M,K] @ B[K,N] + bias[N]
// BM=BN=128, BK=16, 256 threads, 8x8 per thread. (verified R4)
// ---------------------------------------------------------------------------
__global__ __launch_bounds__(256, 2) void gemm_bias_f32(
    const float* __restrict__ A, const float* __restrict__ B,
    const float* __restrict__ bias, float* __restrict__ C,
    int M, int N, int K)
{
  constexpr int BM = 128, BN = 128, BK = 16, TM = 8, TN = 8;
  __shared__ float As[BK][BM];   // transposed A tile
  __shared__ float Bs[BK][BN];
  const int tid = threadIdx.x;
  const int bm = blockIdx.y * BM;
  const int bn = blockIdx.x * BN;
  const int tm = (tid >> 4) * TM;
  const int tn = (tid & 15) * TN;
  float acc[TM][TN] = {};
  for (int k0 = 0; k0 < K; k0 += BK) {
    #pragma unroll
    for (int i = 0; i < 2; ++i) {
      int idx = tid * 2 + i;
      int r = idx >> 2, c4 = idx & 3;
      float4 a = *(const float4*)(A + (size_t)(bm + r) * K + k0 + c4 * 4);
      As[c4 * 4 + 0][r] = a.x;
      As[c4 * 4 + 1][r] = a.y;
      As[c4 * 4 + 2][r] = a.z;
      As[c4 * 4 + 3][r] = a.w;
    }
    #pragma unroll
    for (int i = 0; i < 2; ++i) {
      int idx = tid * 2 + i;
      int r = idx >> 5, c4 = idx & 31;
      *(float4*)&Bs[r][c4 * 4] = *(const float4*)(B + (size_t)(k0 + r) * N + bn + c4 * 4);
    }
    __syncthreads();
    #pragma unroll
    for (int kk = 0; kk < BK; ++kk) {
      float ar[TM], br[TN];
      *(float4*)&ar[0] = *(const float4*)&As[kk][tm];
      *(float4*)&ar[4] = *(const float4*)&As[kk][tm + 4];
      *(float4*)&br[0] = *(const float4*)&Bs[kk][tn];
      *(float4*)&br[4] = *(const float4*)&Bs[kk][tn + 4];
      #pragma unroll
      for (int i = 0; i < TM; ++i)
        #pragma unroll
        for (int j = 0; j < TN; ++j)
          acc[i][j] = fmaf(ar[i], br[j], acc[i][j]);
    }
    __syncthreads();
  }
  #pragma unroll
  for (int i = 0; i < TM; ++i) {
    float* crow = C + (size_t)(bm + tm + i) * N + bn + tn;
    #pragma unroll
    for (int j = 0; j < TN; j += 4) {
      float4 v;
      v.x = acc[i][j + 0] + bias[bn + tn + j + 0];
      v.y = acc[i][j + 1] + bias[bn + tn + j + 1];
      v.z = acc[i][j + 2] + bias[bn + tn + j + 2];
      v.w = acc[i][j + 3] + bias[bn + tn + j + 3];
      *(float4*)(crow + j) = v;
    }
  }
}

// ---------------------------------------------------------------------------
// Persistent LSTM scan (R4 layout + flag-gated sync).
// 256 wgs x 4 waves, one hidden unit per wave; lane: gate g=l>>4, slice
// p=l&15; 64 W_hh weights in VGPRs. Step t: poll flags[t-1][0..255] (one
// dwordx4/lane, s_sleep backoff), then read h row once (sc0sc1) with NaN
// backstop, dot+reduce, activations, store h (system scope), __syncthreads
// (drains vmcnt), tid0 sets flags[t][bid].
// ---------------------------------------------------------------------------
__global__ __launch_bounds__(256, 1) void lstm_scan_kernel(
    const float* __restrict__ xg,      // [T][4096], bias folded in
    const float* __restrict__ Whh,     // [H][4096]
    float* __restrict__ hout,          // [T][H], NaN-filled
    uint32_t* __restrict__ flags,      // [T][NBLK], zero-filled
    int nsteps)
{
  const int tid = threadIdx.x;
  const int w = tid >> 6;           // wave in block
  const int l = tid & 63;
  const int g = l >> 4;             // gate 0..3
  const int p = l & 15;             // h partition
  const int u = blockIdx.x * 4 + w; // hidden unit 0..1023
  const int col = g * HH + u;       // gate column in [0,4096)

  // Preload this lane's 64 weights: rows 4*(p+16k)+e, k=0..15, e=0..3.
  float wr[64];
  #pragma unroll
  for (int k = 0; k < 16; ++k)
    #pragma unroll
    for (int e = 0; e < 4; ++e)
      wr[4 * k + e] = Whh[(size_t)(4 * (p + 16 * k) + e) * G4 + col];

  float c = 0.0f;
  float xgv = xg[col];              // prefetched xg for t=0
  uint32_t budget = (1u << 20);     // anti-hang safety valve

  for (int t = 0; t < nsteps; ++t) {
    float xg_cur = xgv;
    int tnx = (t + 1 < nsteps) ? t + 1 : t;
    xgv = xg[(size_t)tnx * G4 + col];   // prefetch next step's xg

    float red = 0.0f;
    if (t > 0) {
      // --- 1) flag gate: 256 dwords, one dwordx4 per lane ---
      const uint32_t* fa = flags + (size_t)(t - 1) * NBLK + l * 4;
      int fdone = 0;
      do {
        u32x4 f;
        asm volatile("global_load_dwordx4 %0, %1, off sc0 sc1"
                     : "=v"(f) : "v"(fa));
        asm volatile("s_waitcnt vmcnt(0)" ::: "memory");
        __builtin_amdgcn_sched_barrier(0);
        int valid = (f.x != 0u) & (f.y != 0u) & (f.z != 0u) & (f.w != 0u);
        fdone = __all(valid);
        if (!fdone) { --budget; asm volatile("s_sleep 1"); }
      } while (!fdone && budget);

      // --- 2) data sweep (normally once); NaN-sentinel backstop ---
      const float* hrow = hout + (size_t)(t - 1) * HH;
      const float* a0 = hrow + p * 4;   // lane covers floats 4p+64k..+3
      f32x4 hv[16];
      int done = 0;
      do {
        asm volatile(
          "global_load_dwordx4 %0,  %16, off sc0 sc1\n\t"
          "global_load_dwordx4 %1,  %16, off offset:256 sc0 sc1\n\t"
          "global_load_dwordx4 %2,  %16, off offset:512 sc0 sc1\n\t"
          "global_load_dwordx4 %3,  %16, off offset:768 sc0 sc1\n\t"
          "global_load_dwordx4 %4,  %16, off offset:1024 sc0 sc1\n\t"
          "global_load_dwordx4 %5,  %16, off offset:1280 sc0 sc1\n\t"
          "global_load_dwordx4 %6,  %16, off offset:1536 sc0 sc1\n\t"
          "global_load_dwordx4 %7,  %16, off offset:1792 sc0 sc1\n\t"
          "global_load_dwordx4 %8,  %16, off offset:2048 sc0 sc1\n\t"
          "global_load_dwordx4 %9,  %16, off offset:2304 sc0 sc1\n\t"
          "global_load_dwordx4 %10, %16, off offset:2560 sc0 sc1\n\t"
          "global_load_dwordx4 %11, %16, off offset:2816 sc0 sc1\n\t"
          "global_load_dwordx4 %12, %16, off offset:3072 sc0 sc1\n\t"
          "global_load_dwordx4 %13, %16, off offset:3328 sc0 sc1\n\t"
          "global_load_dwordx4 %14, %16, off offset:3584 sc0 sc1\n\t"
          "global_load_dwordx4 %15, %16, off offset:3840 sc0 sc1"
          : "=v"(hv[0]), "=v"(hv[1]), "=v"(hv[2]), "=v"(hv[3]),
            "=v"(hv[4]), "=v"(hv[5]), "=v"(hv[6]), "=v"(hv[7]),
            "=v"(hv[8]), "=v"(hv[9]), "=v"(hv[10]), "=v"(hv[11]),
            "=v"(hv[12]), "=v"(hv[13]), "=v"(hv[14]), "=v"(hv[15])
          : "v"(a0));
        asm volatile("s_waitcnt vmcnt(0)" ::: "memory");
        __builtin_amdgcn_sched_barrier(0);  // rule #18
        int valid = 1;
        #pragma unroll
        for (int k = 0; k < 16; ++k) {
          valid &= (__float_as_uint(hv[k].x) != SENT);
          valid &= (__float_as_uint(hv[k].y) != SENT);
          valid &= (__float_as_uint(hv[k].z) != SENT);
          valid &= (__float_as_uint(hv[k].w) != SENT);
        }
        done = __all(valid);
        if (!done) --budget;
      } while (!done && budget);
      if (!done) {
        // Safety valve: sanitize so we terminate; validation fails loudly.
        #pragma unroll
        for (int k = 0; k < 16; ++k) {
          if (__float_as_uint(hv[k].x) == SENT) hv[k].x = 0.0f;
          if (__float_as_uint(hv[k].y) == SENT) hv[k].y = 0.0f;
          if (__float_as_uint(hv[k].z) == SENT) hv[k].z = 0.0f;
          if (__float_as_uint(hv[k].w) == SENT) hv[k].w = 0.0f;
        }
      }
      // 64 MACs, 4 independent chains
      float s0 = 0.f, s1 = 0.f, s2 = 0.f, s3 = 0.f;
      #pragma unroll
      for (int k = 0; k < 16; ++k) {
        s0 = fmaf(wr[4 * k + 0], hv[k].x, s0);
        s1 = fmaf(wr[4 * k + 1], hv[k].y, s1);
        s2 = fmaf(wr[4 * k + 2], hv[k].z, s2);
        s3 = fmaf(wr[4 * k + 3], hv[k].w, s3);
      }
      red = (s0 + s1) + (s2 + s3);
      #pragma unroll
      for (int m = 1; m < 16; m <<= 1) red += __shfl_xor(red, m, 64);
    }

    float gp = red + xg_cur;
    float gi_ = __shfl(gp, 0, 64);
    float gf_ = __shfl(gp, 16, 64);
    float gg_ = __shfl(gp, 32, 64);
    float go_ = __shfl(gp, 48, 64);
    float iv = sigf(gi_);
    float fv = sigf(gf_);
    float gv = tanhf(gg_);
    float ov = sigf(go_);
    c = fv * c + iv * gv;             // replicated across all 64 lanes
    float h = ov * tanhf(c);
    if (l == 0) {
      __hip_atomic_store(hout + (size_t)t * HH + u, h,
                         __ATOMIC_RELAXED, __HIP_MEMORY_SCOPE_SYSTEM);
    }
    // All 4 waves' h stores drained before the barrier (__syncthreads emits
    // s_waitcnt vmcnt(0) lgkmcnt(0) before s_barrier), then publish flag.
    __syncthreads();
    if (tid == 0) {
      __hip_atomic_store(flags + (size_t)t * NBLK + blockIdx.x, 1u,
                         __ATOMIC_RELAXED, __HIP_MEMORY_SCOPE_SYSTEM);
    }
  }
}

// ---------------------------------------------------------------------------
extern "C" void kernel_launch(void* const* d_in, const int* in_sizes, int n_in,
                              void* d_out, int out_size, void* d_ws, size_t ws_size,
                              hipStream_t stream)
{
  const float* x    = (const float*)d_in[0];
  const float* Wih0 = (const float*)d_in[1];
  const float* Whh0 = (const float*)d_in[2];
  const float* b0   = (const float*)d_in[3];
  const float* Wih1 = (const float*)d_in[4];
  const float* Whh1 = (const float*)d_in[5];
  const float* b1   = (const float*)d_in[6];
  float* out = (float*)d_out;

  float* ws    = (float*)d_ws;
  float* xgbuf = ws;                                   // 128 MB
  float* h1    = ws + (size_t)TT * G4;                 // 32 MB
  uint32_t* flags = (uint32_t*)(ws + (size_t)TT * G4 + (size_t)TT * HH);  // 8 MB

  // 1. inits
  nan_fill_kernel<<<2048, 256, 0, stream>>>(h1, (long)TT * HH);
  nan_fill_kernel<<<2048, 256, 0, stream>>>(out, (long)TT * HH);
  zero_fill_kernel<<<2048, 256, 0, stream>>>(flags, (long)TT * NBLK);

  dim3 gblk(256);
  dim3 ggrid(G4 / 128, TT / 128);

  // 2. xg = x @ W_ih_0 + b_0
  gemm_bias_f32<<<ggrid, gblk, 0, stream>>>(x, Wih0, b0, xgbuf, TT, G4, INDIM);
  // 3. layer-0 scan -> h1
  lstm_scan_kernel<<<NBLK, 256, 0, stream>>>(xgbuf, Whh0, h1, flags, TT);
  // 4. reset flags; xg = h1 @ W_ih_1 + b_1
  zero_fill_kernel<<<2048, 256, 0, stream>>>(flags, (long)TT * NBLK);
  gemm_bias_f32<<<ggrid, gblk, 0, stream>>>(h1, Wih1, b1, xgbuf, TT, G4, HH);
  // 5. layer-1 scan -> d_out
  lstm_scan_kernel<<<NBLK, 256, 0, stream>>>(xgbuf, Whh1, out, flags, TT);
}

// Round 8
// 40009.830 us; speedup vs baseline: 3.7895x; 2.0866x over previous
//
#include <hip/hip_runtime.h>
#include <stdint.h>

// LSTMEncoder: T=8192, IN_DIM=512, H=1024, 2 layers, fp32.
//   1. fill: h1,out <- NaN ; flags <- 0
//   2. gemm: xg = x @ W_ih_0 + b_0
//   3. scan layer 0 -> h1   (flags value 1)
//   4. gemm: xg = h1 @ W_ih_1 + b_1
//   5. scan layer 1 -> out  (flags value 2; no re-zero needed)
// Workspace: xg 128 MB + h1 32 MB + flags 8 MB = 168 MB.
//
// R7 vs R6: R6's data sweep had ~16x request amplification (every lane of
// every wave re-issued the full 16x dwordx4 row read; 64 KB of sc0sc1
// requests per block per step for 4 KB of data) -> fabric congestion,
// 12.5k cycles/step. Now block-cooperative: wave 0 polls flags (1 KB/iter),
// block loads the h row ONCE (256 x dwordx4 = 4 KB) into LDS, waves read
// fragments from LDS. ~13x request-traffic cut.

#define TT    8192
#define INDIM 512
#define HH    1024
#define G4    4096   // 4*H
#define NBLK  256    // scan blocks (= flag row width)

#define SENT 0x7FC00000u  // NaN sentinel bit pattern

typedef float    f32x4 __attribute__((ext_vector_type(4)));
typedef uint32_t u32x4 __attribute__((ext_vector_type(4)));

__device__ __forceinline__ float sigf(float x) { return 1.0f / (1.0f + __expf(-x)); }

// ---------------------------------------------------------------------------
// Pattern fill, 16B per thread-iter, system-scope write-through stores.
// ---------------------------------------------------------------------------
__global__ void fill4_kernel(float* __restrict__ p, long n4, uint32_t pat) {
  float pv = __uint_as_float(pat);
  f32x4 v = { pv, pv, pv, pv };
  long i = (long)blockIdx.x * blockDim.x + threadIdx.x;
  long stride = (long)gridDim.x * blockDim.x;
  for (; i < n4; i += stride) {
    const float* a = p + i * 4;
    asm volatile("global_store_dwordx4 %0, %1, off sc0 sc1" :: "v"(a), "v"(v) : "memory");
  }
}

// ---------------------------------------------------------------------------
// fp32 GEMM with bias: C[M,N] = A[M,K] @ B[K,N] + bias[N]
// BM=BN=128, BK=16, 256 threads, 8x8 per thread. (verified R4/R6)
// ---------------------------------------------------------------------------
__global__ __launch_bounds__(256, 2) void gemm_bias_f32(
    const float* __restrict__ A, const float* __restrict__ B,
    const float* __restrict__ bias, float* __restrict__ C,
    int M, int N, int K)
{
  constexpr int BM = 128, BN = 128, BK = 16, TM = 8, TN = 8;
  __shared__ float As[BK][BM];   // transposed A tile
  __shared__ float Bs[BK][BN];
  const int tid = threadIdx.x;
  const int bm = blockIdx.y * BM;
  const int bn = blockIdx.x * BN;
  const int tm = (tid >> 4) * TM;
  const int tn = (tid & 15) * TN;
  float acc[TM][TN] = {};
  for (int k0 = 0; k0 < K; k0 += BK) {
    #pragma unroll
    for (int i = 0; i < 2; ++i) {
      int idx = tid * 2 + i;
      int r = idx >> 2, c4 = idx & 3;
      float4 a = *(const float4*)(A + (size_t)(bm + r) * K + k0 + c4 * 4);
      As[c4 * 4 + 0][r] = a.x;
      As[c4 * 4 + 1][r] = a.y;
      As[c4 * 4 + 2][r] = a.z;
      As[c4 * 4 + 3][r] = a.w;
    }
    #pragma unroll
    for (int i = 0; i < 2; ++i) {
      int idx = tid * 2 + i;
      int r = idx >> 5, c4 = idx & 31;
      *(float4*)&Bs[r][c4 * 4] = *(const float4*)(B + (size_t)(k0 + r) * N + bn + c4 * 4);
    }
    __syncthreads();
    #pragma unroll
    for (int kk = 0; kk < BK; ++kk) {
      float ar[TM], br[TN];
      *(float4*)&ar[0] = *(const float4*)&As[kk][tm];
      *(float4*)&ar[4] = *(const float4*)&As[kk][tm + 4];
      *(float4*)&br[0] = *(const float4*)&Bs[kk][tn];
      *(float4*)&br[4] = *(const float4*)&Bs[kk][tn + 4];
      #pragma unroll
      for (int i = 0; i < TM; ++i)
        #pragma unroll
        for (int j = 0; j < TN; ++j)
          acc[i][j] = fmaf(ar[i], br[j], acc[i][j]);
    }
    __syncthreads();
  }
  #pragma unroll
  for (int i = 0; i < TM; ++i) {
    float* crow = C + (size_t)(bm + tm + i) * N + bn + tn;
    #pragma unroll
    for (int j = 0; j < TN; j += 4) {
      float4 v;
      v.x = acc[i][j + 0] + bias[bn + tn + j + 0];
      v.y = acc[i][j + 1] + bias[bn + tn + j + 1];
      v.z = acc[i][j + 2] + bias[bn + tn + j + 2];
      v.w = acc[i][j + 3] + bias[bn + tn + j + 3];
      *(float4*)(crow + j) = v;
    }
  }
}

// ---------------------------------------------------------------------------
// Persistent LSTM scan, block-cooperative step.
// 256 wgs x 4 waves, one hidden unit per wave; lane: gate g=l>>4, slice
// p=l&15; 64 W_hh weights in VGPRs. Per step t:
//   wave0 polls flags[t-1][0..255] (one dwordx4/lane = 1 KB/iter, s_sleep
//   backoff) -> __syncthreads -> 256 threads coop-load h row (one dwordx4
//   each, NaN backstop) -> LDS -> __syncthreads -> fragment dot from LDS,
//   shuffle reduce, activations -> store h -> __syncthreads (drains vmcnt)
//   -> tid0 stores flags[t][bid] = fval.
// Layer-versioned flags: poll passes when flag >= fval (layer0 writes 1,
// layer1 writes 2) -> no flag re-zero between layers.
// ---------------------------------------------------------------------------
__global__ __launch_bounds__(256, 1) void lstm_scan_kernel(
    const float* __restrict__ xg,      // [T][4096], bias folded in
    const float* __restrict__ Whh,     // [H][4096]
    float* __restrict__ hout,          // [T][H], NaN-filled
    uint32_t* __restrict__ flags,      // [T][NBLK]
    uint32_t fval, int nsteps)
{
  __shared__ float hsh[HH];            // 4 KB staged h row
  const int tid = threadIdx.x;
  const int w = tid >> 6;              // wave in block
  const int l = tid & 63;
  const int g = l >> 4;                // gate 0..3
  const int p = l & 15;                // h partition
  const int u = blockIdx.x * 4 + w;    // hidden unit 0..1023
  const int col = g * HH + u;          // gate column in [0,4096)

  // Preload this lane's 64 weights: rows 4*(p+16k)+e, k=0..15, e=0..3.
  float wr[64];
  #pragma unroll
  for (int k = 0; k < 16; ++k)
    #pragma unroll
    for (int e = 0; e < 4; ++e)
      wr[4 * k + e] = Whh[(size_t)(4 * (p + 16 * k) + e) * G4 + col];

  float c = 0.0f;
  float xgv = xg[col];              // prefetched xg for t=0
  uint32_t budget = (1u << 20);     // anti-hang safety valve

  for (int t = 0; t < nsteps; ++t) {
    float xg_cur = xgv;
    int tnx = (t + 1 < nsteps) ? t + 1 : t;
    xgv = xg[(size_t)tnx * G4 + col];   // prefetch next step's xg

    float red = 0.0f;
    if (t > 0) {
      // --- 1) flag gate: wave 0 only, 64 lanes x dwordx4 covers 256 flags ---
      if (w == 0) {
        const uint32_t* fa = flags + (size_t)(t - 1) * NBLK + l * 4;
        int fdone = 0;
        do {
          u32x4 f;
          asm volatile("global_load_dwordx4 %0, %1, off sc0 sc1"
                       : "=v"(f) : "v"(fa));
          asm volatile("s_waitcnt vmcnt(0)" ::: "memory");
          __builtin_amdgcn_sched_barrier(0);
          int valid = (f.x >= fval) & (f.y >= fval) & (f.z >= fval) & (f.w >= fval);
          fdone = __all(valid);
          if (!fdone) { --budget; asm volatile("s_sleep 1"); }
        } while (!fdone && budget);
      }
      __syncthreads();   // release all waves once flags pass

      // --- 2) cooperative h-row load, exactly 4 KB per block ---
      {
        const float* ha = hout + (size_t)(t - 1) * HH + tid * 4;
        f32x4 hvv;
        int hd = 0;
        do {
          asm volatile("global_load_dwordx4 %0, %1, off sc0 sc1"
                       : "=v"(hvv) : "v"(ha));
          asm volatile("s_waitcnt vmcnt(0)" ::: "memory");
          __builtin_amdgcn_sched_barrier(0);  // rule #18
          hd = (__float_as_uint(hvv.x) != SENT) & (__float_as_uint(hvv.y) != SENT)
             & (__float_as_uint(hvv.z) != SENT) & (__float_as_uint(hvv.w) != SENT);
          if (!hd) --budget;
        } while (!hd && budget);
        if (!hd) {  // safety valve: terminate; validation fails loudly
          if (__float_as_uint(hvv.x) == SENT) hvv.x = 0.0f;
          if (__float_as_uint(hvv.y) == SENT) hvv.y = 0.0f;
          if (__float_as_uint(hvv.z) == SENT) hvv.z = 0.0f;
          if (__float_as_uint(hvv.w) == SENT) hvv.w = 0.0f;
        }
        *(f32x4*)&hsh[tid * 4] = hvv;
      }
      __syncthreads();

      // --- 3) fragment dot from LDS (broadcast across gate groups) ---
      float s0 = 0.f, s1 = 0.f, s2 = 0.f, s3 = 0.f;
      #pragma unroll
      for (int k = 0; k < 16; ++k) {
        f32x4 hk = *(const f32x4*)&hsh[p * 4 + 64 * k];
        s0 = fmaf(wr[4 * k + 0], hk.x, s0);
        s1 = fmaf(wr[4 * k + 1], hk.y, s1);
        s2 = fmaf(wr[4 * k + 2], hk.z, s2);
        s3 = fmaf(wr[4 * k + 3], hk.w, s3);
      }
      red = (s0 + s1) + (s2 + s3);
      #pragma unroll
      for (int m = 1; m < 16; m <<= 1) red += __shfl_xor(red, m, 64);
    }

    float gp = red + xg_cur;
    float gi_ = __shfl(gp, 0, 64);
    float gf_ = __shfl(gp, 16, 64);
    float gg_ = __shfl(gp, 32, 64);
    float go_ = __shfl(gp, 48, 64);
    float iv = sigf(gi_);
    float fv = sigf(gf_);
    float gv = tanhf(gg_);
    float ov = sigf(go_);
    c = fv * c + iv * gv;             // replicated across all 64 lanes
    float h = ov * tanhf(c);
    if (l == 0) {
      __hip_atomic_store(hout + (size_t)t * HH + u, h,
                         __ATOMIC_RELAXED, __HIP_MEMORY_SCOPE_SYSTEM);
    }
    // __syncthreads emits s_waitcnt vmcnt(0) before s_barrier: all 4 waves'
    // h stores are drained before tid0 publishes the flag.
    __syncthreads();
    if (tid == 0) {
      __hip_atomic_store(flags + (size_t)t * NBLK + blockIdx.x, fval,
                         __ATOMIC_RELAXED, __HIP_MEMORY_SCOPE_SYSTEM);
    }
  }
}

// ---------------------------------------------------------------------------
extern "C" void kernel_launch(void* const* d_in, const int* in_sizes, int n_in,
                              void* d_out, int out_size, void* d_ws, size_t ws_size,
                              hipStream_t stream)
{
  const float* x    = (const float*)d_in[0];
  const float* Wih0 = (const float*)d_in[1];
  const float* Whh0 = (const float*)d_in[2];
  const float* b0   = (const float*)d_in[3];
  const float* Wih1 = (const float*)d_in[4];
  const float* Whh1 = (const float*)d_in[5];
  const float* b1   = (const float*)d_in[6];
  float* out = (float*)d_out;

  float* ws    = (float*)d_ws;
  float* xgbuf = ws;                                   // 128 MB
  float* h1    = ws + (size_t)TT * G4;                 // 32 MB
  uint32_t* flags = (uint32_t*)(ws + (size_t)TT * G4 + (size_t)TT * HH);  // 8 MB

  // 1. inits: h buffers <- NaN sentinel, flags <- 0
  fill4_kernel<<<2048, 256, 0, stream>>>(h1, (long)TT * HH / 4, SENT);
  fill4_kernel<<<2048, 256, 0, stream>>>(out, (long)TT * HH / 4, SENT);
  fill4_kernel<<<2048, 256, 0, stream>>>((float*)flags, (long)TT * NBLK / 4, 0u);

  dim3 gblk(256);
  dim3 ggrid(G4 / 128, TT / 128);

  // 2. xg = x @ W_ih_0 + b_0
  gemm_bias_f32<<<ggrid, gblk, 0, stream>>>(x, Wih0, b0, xgbuf, TT, G4, INDIM);
  // 3. layer-0 scan -> h1 (flag value 1)
  lstm_scan_kernel<<<NBLK, 256, 0, stream>>>(xgbuf, Whh0, h1, flags, 1u, TT);
  // 4. xg = h1 @ W_ih_1 + b_1
  gemm_bias_f32<<<ggrid, gblk, 0, stream>>>(h1, Wih1, b1, xgbuf, TT, G4, HH);
  // 5. layer-1 scan -> d_out (flag value 2; no re-zero)
  lstm_scan_kernel<<<NBLK, 256, 0, stream>>>(xgbuf, Whh1, out, flags, 2u, TT);
}

// Round 9
// 38652.240 us; speedup vs baseline: 3.9226x; 1.0351x over previous
//
#include <hip/hip_runtime.h>
#include <stdint.h>

// LSTMEncoder: T=8192, IN_DIM=512, H=1024, 2 layers, fp32.
//   1. fill: h1,out <- NaN
//   2. gemm: xg = x @ W_ih_0 + b_0
//   3. scan layer 0 -> h1
//   4. gemm: xg = h1 @ W_ih_1 + b_1
//   5. scan layer 1 -> out
// Workspace: xg 128 MB + h1 32 MB = 160 MB.
//
// R9 vs R8: R8's flag protocol cost 3 serialized fabric round trips per
// step (store-drain, flag hop, data fetch) -> 2.4 us/step. Now data IS the
// flag again (R4 semantics) but with R7's cooperative load: each thread
// polls only ITS OWN 16B of the h row (256 req/block/sweep, the proven R8
// poll rate), stages to LDS. Producer fire-and-forget h store. One RT.

#define TT    8192
#define INDIM 512
#define HH    1024
#define G4    4096   // 4*H
#define NBLK  256    // scan blocks

#define SENT 0x7FC00000u  // NaN sentinel bit pattern

typedef float f32x4 __attribute__((ext_vector_type(4)));

__device__ __forceinline__ float sigf(float x) { return 1.0f / (1.0f + __expf(-x)); }

// ---------------------------------------------------------------------------
// Pattern fill, 16B per thread-iter, system-scope write-through stores.
// ---------------------------------------------------------------------------
__global__ void fill4_kernel(float* __restrict__ p, long n4, uint32_t pat) {
  float pv = __uint_as_float(pat);
  f32x4 v = { pv, pv, pv, pv };
  long i = (long)blockIdx.x * blockDim.x + threadIdx.x;
  long stride = (long)gridDim.x * blockDim.x;
  for (; i < n4; i += stride) {
    const float* a = p + i * 4;
    asm volatile("global_store_dwordx4 %0, %1, off sc0 sc1" :: "v"(a), "v"(v) : "memory");
  }
}

// ---------------------------------------------------------------------------
// fp32 GEMM with bias: C[M,N] = A[M,K] @ B[K,N] + bias[N]
// BM=BN=128, BK=16, 256 threads, 8x8 per thread. (verified R4/R6/R8)
// ---------------------------------------------------------------------------
__global__ __launch_bounds__(256, 2) void gemm_bias_f32(
    const float* __restrict__ A, const float* __restrict__ B,
    const float* __restrict__ bias, float* __restrict__ C,
    int M, int N, int K)
{
  constexpr int BM = 128, BN = 128, BK = 16, TM = 8, TN = 8;
  __shared__ float As[BK][BM];   // transposed A tile
  __shared__ float Bs[BK][BN];
  const int tid = threadIdx.x;
  const int bm = blockIdx.y * BM;
  const int bn = blockIdx.x * BN;
  const int tm = (tid >> 4) * TM;
  const int tn = (tid & 15) * TN;
  float acc[TM][TN] = {};
  for (int k0 = 0; k0 < K; k0 += BK) {
    #pragma unroll
    for (int i = 0; i < 2; ++i) {
      int idx = tid * 2 + i;
      int r = idx >> 2, c4 = idx & 3;
      float4 a = *(const float4*)(A + (size_t)(bm + r) * K + k0 + c4 * 4);
      As[c4 * 4 + 0][r] = a.x;
      As[c4 * 4 + 1][r] = a.y;
      As[c4 * 4 + 2][r] = a.z;
      As[c4 * 4 + 3][r] = a.w;
    }
    #pragma unroll
    for (int i = 0; i < 2; ++i) {
      int idx = tid * 2 + i;
      int r = idx >> 5, c4 = idx & 31;
      *(float4*)&Bs[r][c4 * 4] = *(const float4*)(B + (size_t)(k0 + r) * N + bn + c4 * 4);
    }
    __syncthreads();
    #pragma unroll
    for (int kk = 0; kk < BK; ++kk) {
      float ar[TM], br[TN];
      *(float4*)&ar[0] = *(const float4*)&As[kk][tm];
      *(float4*)&ar[4] = *(const float4*)&As[kk][tm + 4];
      *(float4*)&br[0] = *(const float4*)&Bs[kk][tn];
      *(float4*)&br[4] = *(const float4*)&Bs[kk][tn + 4];
      #pragma unroll
      for (int i = 0; i < TM; ++i)
        #pragma unroll
        for (int j = 0; j < TN; ++j)
          acc[i][j] = fmaf(ar[i], br[j], acc[i][j]);
    }
    __syncthreads();
  }
  #pragma unroll
  for (int i = 0; i < TM; ++i) {
    float* crow = C + (size_t)(bm + tm + i) * N + bn + tn;
    #pragma unroll
    for (int j = 0; j < TN; j += 4) {
      float4 v;
      v.x = acc[i][j + 0] + bias[bn + tn + j + 0];
      v.y = acc[i][j + 1] + bias[bn + tn + j + 1];
      v.z = acc[i][j + 2] + bias[bn + tn + j + 2];
      v.w = acc[i][j + 3] + bias[bn + tn + j + 3];
      *(float4*)(crow + j) = v;
    }
  }
}

// ---------------------------------------------------------------------------
// Persistent LSTM scan, sentinel dataflow + cooperative staging.
// 256 wgs x 4 waves, one hidden unit per wave; lane: gate g=l>>4, slice
// p=l&15; 64 W_hh weights in VGPRs. Per step t:
//   each thread polls ITS OWN dwordx4 of h[t-1] (sc0sc1) until all 4
//   floats are non-sentinel (data is its own flag; h dwords are written
//   once, atomically) -> barrier W (prior LDS reads done) -> stage to LDS
//   -> barrier R -> fragment dot from LDS, shuffle reduce, activations ->
//   lane0 stores h[t][u] system-scope, fire-and-forget.
// Critical path: ONE store->load visibility hop + compute.
// ---------------------------------------------------------------------------
__global__ __launch_bounds__(256, 1) void lstm_scan_kernel(
    const float* __restrict__ xg,      // [T][4096], bias folded in
    const float* __restrict__ Whh,     // [H][4096]
    float* __restrict__ hout,          // [T][H], NaN-filled
    int nsteps)
{
  __shared__ float hsh[HH];            // 4 KB staged h row
  const int tid = threadIdx.x;
  const int w = tid >> 6;              // wave in block
  const int l = tid & 63;
  const int g = l >> 4;                // gate 0..3
  const int p = l & 15;                // h partition
  const int u = blockIdx.x * 4 + w;    // hidden unit 0..1023
  const int col = g * HH + u;          // gate column in [0,4096)

  // Preload this lane's 64 weights: rows 4*(p+16k)+e, k=0..15, e=0..3.
  float wr[64];
  #pragma unroll
  for (int k = 0; k < 16; ++k)
    #pragma unroll
    for (int e = 0; e < 4; ++e)
      wr[4 * k + e] = Whh[(size_t)(4 * (p + 16 * k) + e) * G4 + col];

  float c = 0.0f;
  float xgv = xg[col];              // prefetched xg for t=0
  uint32_t budget = (1u << 20);     // anti-hang safety valve

  for (int t = 0; t < nsteps; ++t) {
    float xg_cur = xgv;
    int tnx = (t + 1 < nsteps) ? t + 1 : t;
    xgv = xg[(size_t)tnx * G4 + col];   // prefetch next step's xg

    float red = 0.0f;
    if (t > 0) {
      // --- 1) poll own 16B of h[t-1]; the poll IS the data load ---
      const float* ha = hout + (size_t)(t - 1) * HH + tid * 4;
      f32x4 hvv;
      int hd = 0;
      do {
        asm volatile("global_load_dwordx4 %0, %1, off sc0 sc1"
                     : "=v"(hvv) : "v"(ha));
        asm volatile("s_waitcnt vmcnt(0)" ::: "memory");
        __builtin_amdgcn_sched_barrier(0);  // rule #18
        hd = (__float_as_uint(hvv.x) != SENT) & (__float_as_uint(hvv.y) != SENT)
           & (__float_as_uint(hvv.z) != SENT) & (__float_as_uint(hvv.w) != SENT);
        if (!hd) --budget;
      } while (!hd && budget);
      if (!hd) {  // safety valve: terminate; validation fails loudly
        if (__float_as_uint(hvv.x) == SENT) hvv.x = 0.0f;
        if (__float_as_uint(hvv.y) == SENT) hvv.y = 0.0f;
        if (__float_as_uint(hvv.z) == SENT) hvv.z = 0.0f;
        if (__float_as_uint(hvv.w) == SENT) hvv.w = 0.0f;
      }
      __syncthreads();               // W: step t-1's LDS reads complete
      *(f32x4*)&hsh[tid * 4] = hvv;
      __syncthreads();               // R: full row staged

      // --- 2) fragment dot from LDS (broadcast across gate groups) ---
      float s0 = 0.f, s1 = 0.f, s2 = 0.f, s3 = 0.f;
      #pragma unroll
      for (int k = 0; k < 16; ++k) {
        f32x4 hk = *(const f32x4*)&hsh[p * 4 + 64 * k];
        s0 = fmaf(wr[4 * k + 0], hk.x, s0);
        s1 = fmaf(wr[4 * k + 1], hk.y, s1);
        s2 = fmaf(wr[4 * k + 2], hk.z, s2);
        s3 = fmaf(wr[4 * k + 3], hk.w, s3);
      }
      red = (s0 + s1) + (s2 + s3);
      #pragma unroll
      for (int m = 1; m < 16; m <<= 1) red += __shfl_xor(red, m, 64);
    }

    float gp = red + xg_cur;
    float gi_ = __shfl(gp, 0, 64);
    float gf_ = __shfl(gp, 16, 64);
    float gg_ = __shfl(gp, 32, 64);
    float go_ = __shfl(gp, 48, 64);
    float iv = sigf(gi_);
    float fv = sigf(gf_);
    float gv = tanhf(gg_);
    float ov = sigf(go_);
    c = fv * c + iv * gv;             // replicated across all 64 lanes
    float h = ov * tanhf(c);
    if (l == 0) {                     // fire-and-forget; data is its own flag
      __hip_atomic_store(hout + (size_t)t * HH + u, h,
                         __ATOMIC_RELAXED, __HIP_MEMORY_SCOPE_SYSTEM);
    }
  }
}

// ---------------------------------------------------------------------------
extern "C" void kernel_launch(void* const* d_in, const int* in_sizes, int n_in,
                              void* d_out, int out_size, void* d_ws, size_t ws_size,
                              hipStream_t stream)
{
  const float* x    = (const float*)d_in[0];
  const float* Wih0 = (const float*)d_in[1];
  const float* Whh0 = (const float*)d_in[2];
  const float* b0   = (const float*)d_in[3];
  const float* Wih1 = (const float*)d_in[4];
  const float* Whh1 = (const float*)d_in[5];
  const float* b1   = (const float*)d_in[6];
  float* out = (float*)d_out;

  float* ws    = (float*)d_ws;
  float* xgbuf = ws;                        // 128 MB
  float* h1    = ws + (size_t)TT * G4;      // 32 MB

  // 1. inits: h buffers <- NaN sentinel
  fill4_kernel<<<2048, 256, 0, stream>>>(h1, (long)TT * HH / 4, SENT);
  fill4_kernel<<<2048, 256, 0, stream>>>(out, (long)TT * HH / 4, SENT);

  dim3 gblk(256);
  dim3 ggrid(G4 / 128, TT / 128);

  // 2. xg = x @ W_ih_0 + b_0
  gemm_bias_f32<<<ggrid, gblk, 0, stream>>>(x, Wih0, b0, xgbuf, TT, G4, INDIM);
  // 3. layer-0 scan -> h1
  lstm_scan_kernel<<<NBLK, 256, 0, stream>>>(xgbuf, Whh0, h1, TT);
  // 4. xg = h1 @ W_ih_1 + b_1
  gemm_bias_f32<<<ggrid, gblk, 0, stream>>>(h1, Wih1, b1, xgbuf, TT, G4, HH);
  // 5. layer-1 scan -> d_out
  lstm_scan_kernel<<<NBLK, 256, 0, stream>>>(xgbuf, Whh1, out, TT);
}

// Round 10
// 37301.642 us; speedup vs baseline: 4.0647x; 1.0362x over previous
//
#include <hip/hip_runtime.h>
#include <stdint.h>

// LSTMEncoder: T=8192, IN_DIM=512, H=1024, 2 layers, fp32.
//   1. fill: h1,out <- NaN
//   2. gemm: xg = x @ W_ih_0 + b_0
//   3. fused scan: blocks 0-255 layer 0 -> h1; blocks 256-511 layer 1 -> out
//      (layer 1 computes its input projection on the fly from h1[t]; GEMM2
//       eliminated; both layers advance concurrently, one step-latency apart)
// Workspace: xg 128 MB + h1 32 MB = 160 MB.
//
// R10 vs R9: R8/R9 pinned at identical 2.4 us/step under two different sync
// protocols -> the floor is the per-step global visibility hop, not the
// protocol. Can't shrink the hop; stop paying it twice: pipeline the two
// layers (2 x 19.6 ms serial -> ~1 x 20 ms concurrent) and fold GEMM2 into
// layer-1's per-step register dot.

#define TT    8192
#define INDIM 512
#define HH    1024
#define G4    4096   // 4*H
#define NBLK  256    // blocks per layer

#define SENT 0x7FC00000u  // NaN sentinel bit pattern

typedef float f32x4 __attribute__((ext_vector_type(4)));

__device__ __forceinline__ float sigf(float x) { return 1.0f / (1.0f + __expf(-x)); }
// clamped tanh via __expf: exact +-1 beyond |x|>20, no libm call, no overflow
__device__ __forceinline__ float tanhfast(float x) {
  x = fminf(fmaxf(x, -20.0f), 20.0f);
  float e = __expf(2.0f * x);
  return (e - 1.0f) / (e + 1.0f);
}

// ---------------------------------------------------------------------------
// Pattern fill, 16B per thread-iter, system-scope write-through stores.
// ---------------------------------------------------------------------------
__global__ void fill4_kernel(float* __restrict__ p, long n4, uint32_t pat) {
  float pv = __uint_as_float(pat);
  f32x4 v = { pv, pv, pv, pv };
  long i = (long)blockIdx.x * blockDim.x + threadIdx.x;
  long stride = (long)gridDim.x * blockDim.x;
  for (; i < n4; i += stride) {
    const float* a = p + i * 4;
    asm volatile("global_store_dwordx4 %0, %1, off sc0 sc1" :: "v"(a), "v"(v) : "memory");
  }
}

// ---------------------------------------------------------------------------
// fp32 GEMM with bias: C[M,N] = A[M,K] @ B[K,N] + bias[N]
// BM=BN=128, BK=16, 256 threads, 8x8 per thread. (verified R4/R6/R8/R9)
// ---------------------------------------------------------------------------
__global__ __launch_bounds__(256, 2) void gemm_bias_f32(
    const float* __restrict__ A, const float* __restrict__ B,
    const float* __restrict__ bias, float* __restrict__ C,
    int M, int N, int K)
{
  constexpr int BM = 128, BN = 128, BK = 16, TM = 8, TN = 8;
  __shared__ float As[BK][BM];   // transposed A tile
  __shared__ float Bs[BK][BN];
  const int tid = threadIdx.x;
  const int bm = blockIdx.y * BM;
  const int bn = blockIdx.x * BN;
  const int tm = (tid >> 4) * TM;
  const int tn = (tid & 15) * TN;
  float acc[TM][TN] = {};
  for (int k0 = 0; k0 < K; k0 += BK) {
    #pragma unroll
    for (int i = 0; i < 2; ++i) {
      int idx = tid * 2 + i;
      int r = idx >> 2, c4 = idx & 3;
      float4 a = *(const float4*)(A + (size_t)(bm + r) * K + k0 + c4 * 4);
      As[c4 * 4 + 0][r] = a.x;
      As[c4 * 4 + 1][r] = a.y;
      As[c4 * 4 + 2][r] = a.z;
      As[c4 * 4 + 3][r] = a.w;
    }
    #pragma unroll
    for (int i = 0; i < 2; ++i) {
      int idx = tid * 2 + i;
      int r = idx >> 5, c4 = idx & 31;
      *(float4*)&Bs[r][c4 * 4] = *(const float4*)(B + (size_t)(k0 + r) * N + bn + c4 * 4);
    }
    __syncthreads();
    #pragma unroll
    for (int kk = 0; kk < BK; ++kk) {
      float ar[TM], br[TN];
      *(float4*)&ar[0] = *(const float4*)&As[kk][tm];
      *(float4*)&ar[4] = *(const float4*)&As[kk][tm + 4];
      *(float4*)&br[0] = *(const float4*)&Bs[kk][tn];
      *(float4*)&br[4] = *(const float4*)&Bs[kk][tn + 4];
      #pragma unroll
      for (int i = 0; i < TM; ++i)
        #pragma unroll
        for (int j = 0; j < TN; ++j)
          acc[i][j] = fmaf(ar[i], br[j], acc[i][j]);
    }
    __syncthreads();
  }
  #pragma unroll
  for (int i = 0; i < TM; ++i) {
    float* crow = C + (size_t)(bm + tm + i) * N + bn + tn;
    #pragma unroll
    for (int j = 0; j < TN; j += 4) {
      float4 v;
      v.x = acc[i][j + 0] + bias[bn + tn + j + 0];
      v.y = acc[i][j + 1] + bias[bn + tn + j + 1];
      v.z = acc[i][j + 2] + bias[bn + tn + j + 2];
      v.w = acc[i][j + 3] + bias[bn + tn + j + 3];
      *(float4*)(crow + j) = v;
    }
  }
}

// ---------------------------------------------------------------------------
// Fused 2-layer persistent scan. 512 blocks x 256 threads, 2 blocks/CU
// (launch_bounds(256,2) caps VGPR<=256 -> 8 waves/CU -> all co-resident).
// Blocks 0-255: layer 0 (R9-proven body): poll own 16B of h1[t-1], stage
//   to LDS, dot(W_hh_0) from VGPRs, activations, store h1[t][u].
// Blocks 256-511: layer 1: poll own 16B of BOTH h1[t] and h2[t-1], stage
//   both to LDS, red = dot(W_ih_1, h1[t]) + dot(W_hh_1, h2[t-1]) + b1,
//   activations, store h2[t][u] (= d_out).
// Data is its own flag (NaN sentinel, each dword written once, sc0sc1).
// ---------------------------------------------------------------------------
__global__ __launch_bounds__(256, 2) void lstm_fused_kernel(
    const float* __restrict__ xg,      // [T][4096] layer-0 input proj (b0 folded)
    const float* __restrict__ Whh0,    // [H][4096]
    const float* __restrict__ Wih1,    // [H][4096]
    const float* __restrict__ Whh1,    // [H][4096]
    const float* __restrict__ b1,      // [4096]
    float* __restrict__ h1buf,         // [T][H], NaN-filled
    float* __restrict__ h2buf,         // [T][H] = d_out, NaN-filled
    int nsteps)
{
  __shared__ float sh1[HH];            // staged row (layer0: h[t-1]; layer1: h1[t])
  __shared__ float sh2[HH];            // layer1: h2[t-1]
  const int tid = threadIdx.x;
  const int w = tid >> 6;              // wave in block
  const int l = tid & 63;
  const int g = l >> 4;                // gate 0..3
  const int p = l & 15;                // h partition
  const int lay = blockIdx.x >> 8;     // 0 or 1
  const int bid = blockIdx.x & 255;
  const int u = bid * 4 + w;           // hidden unit 0..1023
  const int col = g * HH + u;          // gate column in [0,4096)

  uint32_t budget = (1u << 20);        // anti-hang safety valve
  float c = 0.0f;

  if (lay == 0) {
    // ------------------------- layer 0 (R9 body) -------------------------
    float wr[64];
    #pragma unroll
    for (int k = 0; k < 16; ++k)
      #pragma unroll
      for (int e = 0; e < 4; ++e)
        wr[4 * k + e] = Whh0[(size_t)(4 * (p + 16 * k) + e) * G4 + col];

    float xgv = xg[col];
    for (int t = 0; t < nsteps; ++t) {
      float xg_cur = xgv;
      int tnx = (t + 1 < nsteps) ? t + 1 : t;
      xgv = xg[(size_t)tnx * G4 + col];

      float red = 0.0f;
      if (t > 0) {
        const float* ha = h1buf + (size_t)(t - 1) * HH + tid * 4;
        f32x4 hvv;
        int hd = 0;
        do {
          asm volatile("global_load_dwordx4 %0, %1, off sc0 sc1"
                       : "=v"(hvv) : "v"(ha));
          asm volatile("s_waitcnt vmcnt(0)" ::: "memory");
          __builtin_amdgcn_sched_barrier(0);  // rule #18
          hd = (__float_as_uint(hvv.x) != SENT) & (__float_as_uint(hvv.y) != SENT)
             & (__float_as_uint(hvv.z) != SENT) & (__float_as_uint(hvv.w) != SENT);
          if (!hd) --budget;
        } while (!hd && budget);
        if (!hd) {
          if (__float_as_uint(hvv.x) == SENT) hvv.x = 0.0f;
          if (__float_as_uint(hvv.y) == SENT) hvv.y = 0.0f;
          if (__float_as_uint(hvv.z) == SENT) hvv.z = 0.0f;
          if (__float_as_uint(hvv.w) == SENT) hvv.w = 0.0f;
        }
        __syncthreads();               // W: prior LDS reads done
        *(f32x4*)&sh1[tid * 4] = hvv;
        __syncthreads();               // R: row staged

        float s0 = 0.f, s1 = 0.f, s2 = 0.f, s3 = 0.f;
        #pragma unroll
        for (int k = 0; k < 16; ++k) {
          f32x4 hk = *(const f32x4*)&sh1[p * 4 + 64 * k];
          s0 = fmaf(wr[4 * k + 0], hk.x, s0);
          s1 = fmaf(wr[4 * k + 1], hk.y, s1);
          s2 = fmaf(wr[4 * k + 2], hk.z, s2);
          s3 = fmaf(wr[4 * k + 3], hk.w, s3);
        }
        red = (s0 + s1) + (s2 + s3);
        #pragma unroll
        for (int m = 1; m < 16; m <<= 1) red += __shfl_xor(red, m, 64);
      }

      float gp = red + xg_cur;
      float gi_ = __shfl(gp, 0, 64);
      float gf_ = __shfl(gp, 16, 64);
      float gg_ = __shfl(gp, 32, 64);
      float go_ = __shfl(gp, 48, 64);
      float iv = sigf(gi_);
      float fv = sigf(gf_);
      float gv = tanhfast(gg_);
      float ov = sigf(go_);
      c = fv * c + iv * gv;
      float h = ov * tanhfast(c);
      if (l == 0) {
        __hip_atomic_store(h1buf + (size_t)t * HH + u, h,
                           __ATOMIC_RELAXED, __HIP_MEMORY_SCOPE_SYSTEM);
      }
    }
  } else {
    // ------------------------- layer 1 -------------------------
    float wr_hh[64], wr_ih[64];
    #pragma unroll
    for (int k = 0; k < 16; ++k)
      #pragma unroll
      for (int e = 0; e < 4; ++e) {
        size_t row = (size_t)(4 * (p + 16 * k) + e);
        wr_hh[4 * k + e] = Whh1[row * G4 + col];
        wr_ih[4 * k + e] = Wih1[row * G4 + col];
      }
    const float bv = b1[col];

    for (int t = 0; t < nsteps; ++t) {
      // poll own 16B of h1[t] (and h2[t-1] when t>0); data is its own flag
      const float* ha1 = h1buf + (size_t)t * HH + tid * 4;
      const float* ha2 = h2buf + (size_t)(t - 1) * HH + tid * 4;
      f32x4 v1, v2;
      int hd = 0;
      if (t > 0) {
        do {
          asm volatile("global_load_dwordx4 %0, %2, off sc0 sc1\n\t"
                       "global_load_dwordx4 %1, %3, off sc0 sc1"
                       : "=v"(v1), "=v"(v2) : "v"(ha1), "v"(ha2));
          asm volatile("s_waitcnt vmcnt(0)" ::: "memory");
          __builtin_amdgcn_sched_barrier(0);
          hd = (__float_as_uint(v1.x) != SENT) & (__float_as_uint(v1.y) != SENT)
             & (__float_as_uint(v1.z) != SENT) & (__float_as_uint(v1.w) != SENT)
             & (__float_as_uint(v2.x) != SENT) & (__float_as_uint(v2.y) != SENT)
             & (__float_as_uint(v2.z) != SENT) & (__float_as_uint(v2.w) != SENT);
          if (!hd) --budget;
        } while (!hd && budget);
      } else {
        do {
          asm volatile("global_load_dwordx4 %0, %1, off sc0 sc1"
                       : "=v"(v1) : "v"(ha1));
          asm volatile("s_waitcnt vmcnt(0)" ::: "memory");
          __builtin_amdgcn_sched_barrier(0);
          hd = (__float_as_uint(v1.x) != SENT) & (__float_as_uint(v1.y) != SENT)
             & (__float_as_uint(v1.z) != SENT) & (__float_as_uint(v1.w) != SENT);
          if (!hd) --budget;
        } while (!hd && budget);
        v2 = f32x4{0.f, 0.f, 0.f, 0.f};
      }
      if (!hd) {  // safety valve
        if (__float_as_uint(v1.x) == SENT) v1.x = 0.0f;
        if (__float_as_uint(v1.y) == SENT) v1.y = 0.0f;
        if (__float_as_uint(v1.z) == SENT) v1.z = 0.0f;
        if (__float_as_uint(v1.w) == SENT) v1.w = 0.0f;
        if (__float_as_uint(v2.x) == SENT) v2.x = 0.0f;
        if (__float_as_uint(v2.y) == SENT) v2.y = 0.0f;
        if (__float_as_uint(v2.z) == SENT) v2.z = 0.0f;
        if (__float_as_uint(v2.w) == SENT) v2.w = 0.0f;
      }
      __syncthreads();               // W: prior LDS reads done
      *(f32x4*)&sh1[tid * 4] = v1;
      *(f32x4*)&sh2[tid * 4] = v2;
      __syncthreads();               // R: rows staged

      float s0 = 0.f, s1 = 0.f, s2 = 0.f, s3 = 0.f;
      #pragma unroll
      for (int k = 0; k < 16; ++k) {
        f32x4 a = *(const f32x4*)&sh1[p * 4 + 64 * k];
        f32x4 b = *(const f32x4*)&sh2[p * 4 + 64 * k];
        s0 = fmaf(wr_ih[4 * k + 0], a.x, s0);
        s1 = fmaf(wr_ih[4 * k + 1], a.y, s1);
        s2 = fmaf(wr_ih[4 * k + 2], a.z, s2);
        s3 = fmaf(wr_ih[4 * k + 3], a.w, s3);
        s0 = fmaf(wr_hh[4 * k + 0], b.x, s0);
        s1 = fmaf(wr_hh[4 * k + 1], b.y, s1);
        s2 = fmaf(wr_hh[4 * k + 2], b.z, s2);
        s3 = fmaf(wr_hh[4 * k + 3], b.w, s3);
      }
      float red = (s0 + s1) + (s2 + s3);
      #pragma unroll
      for (int m = 1; m < 16; m <<= 1) red += __shfl_xor(red, m, 64);

      float gp = red + bv;
      float gi_ = __shfl(gp, 0, 64);
      float gf_ = __shfl(gp, 16, 64);
      float gg_ = __shfl(gp, 32, 64);
      float go_ = __shfl(gp, 48, 64);
      float iv = sigf(gi_);
      float fv = sigf(gf_);
      float gv = tanhfast(gg_);
      float ov = sigf(go_);
      c = fv * c + iv * gv;
      float h = ov * tanhfast(c);
      if (l == 0) {
        __hip_atomic_store(h2buf + (size_t)t * HH + u, h,
                           __ATOMIC_RELAXED, __HIP_MEMORY_SCOPE_SYSTEM);
      }
    }
  }
}

// ---------------------------------------------------------------------------
extern "C" void kernel_launch(void* const* d_in, const int* in_sizes, int n_in,
                              void* d_out, int out_size, void* d_ws, size_t ws_size,
                              hipStream_t stream)
{
  const float* x    = (const float*)d_in[0];
  const float* Wih0 = (const float*)d_in[1];
  const float* Whh0 = (const float*)d_in[2];
  const float* b0   = (const float*)d_in[3];
  const float* Wih1 = (const float*)d_in[4];
  const float* Whh1 = (const float*)d_in[5];
  const float* b1   = (const float*)d_in[6];
  float* out = (float*)d_out;

  float* ws    = (float*)d_ws;
  float* xgbuf = ws;                        // 128 MB (layer-0 input proj)
  float* h1    = ws + (size_t)TT * G4;      // 32 MB

  // 1. inits: h buffers <- NaN sentinel
  fill4_kernel<<<2048, 256, 0, stream>>>(h1, (long)TT * HH / 4, SENT);
  fill4_kernel<<<2048, 256, 0, stream>>>(out, (long)TT * HH / 4, SENT);

  dim3 gblk(256);
  dim3 ggrid(G4 / 128, TT / 128);

  // 2. xg = x @ W_ih_0 + b_0
  gemm_bias_f32<<<ggrid, gblk, 0, stream>>>(x, Wih0, b0, xgbuf, TT, G4, INDIM);
  // 3. fused 2-layer scan (512 blocks: 0-255 layer0, 256-511 layer1)
  lstm_fused_kernel<<<2 * NBLK, 256, 0, stream>>>(
      xgbuf, Whh0, Wih1, Whh1, b1, h1, out, TT);
}